// Round 8
// baseline (600.981 us; speedup 1.0000x reference)
//
#include <hip/hip_runtime.h>
#include <stdint.h>

// Problem constants (N,C,H,W) = (32,256,56,56), 3x3 conv pad=1 stride=1
#define NB    32
#define C     256
#define HH    56
#define WW    56
#define HW    3136        // 56*56
#define P_TOT 100352      // NB*HW
#define PW    58          // halo-padded width
#define PHW   3364        // 58*58
#define NPAD  107648      // NB*PHW
#define EPSBN 1e-5f

// ---------------- 64-lane u64 shuffle + 64x64 bit-matrix transpose -----------
__device__ __forceinline__ uint64_t shflx64(uint64_t v, int m) {
    int lo = __shfl_xor((int)(uint32_t)v, m, 64);
    int hi = __shfl_xor((int)(uint32_t)(v >> 32), m, 64);
    return ((uint64_t)(uint32_t)hi << 32) | (uint32_t)lo;
}
// Input: lane i holds bits j. Output: lane j holds bits i.
__device__ __forceinline__ uint64_t bt64(uint64_t M, int lane) {
    const uint64_t mk[6] = {0x5555555555555555ULL, 0x3333333333333333ULL,
                            0x0F0F0F0F0F0F0F0FULL, 0x00FF00FF00FF00FFULL,
                            0x0000FFFF0000FFFFULL, 0x00000000FFFFFFFFULL};
#pragma unroll
    for (int k = 0; k < 6; ++k) {
        int s = 1 << k;
        uint64_t mA = mk[k];
        uint64_t v = shflx64(M, s);
        M = (lane & s) ? ((M & ~mA) | ((v & ~mA) >> s))
                       : ((M &  mA) | ((v &  mA) << s));
    }
    return M;
}

// ============ pack weights (both sets) via ballot: 1 wave per (set,co,t,wd) ==
// pwt layout: [co][40] u64, slot wd*9 + t (t = ty*3+tx); 320B stride per co.
__global__ __launch_bounds__(256) void pack_wgt(const float* __restrict__ w1,
                                                const float* __restrict__ w2,
                                                uint64_t* __restrict__ pw1,
                                                uint64_t* __restrict__ pw2,
                                                int* __restrict__ pc1,
                                                int* __restrict__ pc2) {
    int gw = blockIdx.x * 4 + (threadIdx.x >> 6);   // global wave 0..18431
    int lane = threadIdx.x & 63;
    int set = gw / 9216;
    int r = gw - set * 9216;
    int wd = r & 3, q = r >> 2;
    int t = q % 9, co = q / 9;
    const float* w = set ? w2 : w1;
    float v = w[(size_t)co * 2304 + (size_t)(wd * 64 + lane) * 9 + t];
    unsigned long long m = __ballot(v >= 0.0f);
    if (lane == 0) {
        uint64_t* pw = set ? pw2 : pw1;
        int* pc = set ? pc2 : pc1;
        pw[(size_t)co * 40 + wd * 9 + t] = m;
        pc[(co * 9 + t) * 4 + wd] = (int)__popcll(m);
    }
}

// == border-correction K[pat][co] = 256*Tvalid + 2*sum_{t inv} popc(w_t),
//    plus zeroing of the fused-stats accumulators (block 18) ==================
__global__ __launch_bounds__(256) void build_K(const int* __restrict__ pc1,
                                               const int* __restrict__ pc2,
                                               unsigned short* __restrict__ K1,
                                               unsigned short* __restrict__ K2,
                                               int* __restrict__ sS1,
                                               unsigned long long* __restrict__ sQ1,
                                               int* __restrict__ sS2,
                                               unsigned long long* __restrict__ sQ2) {
    if (blockIdx.x == 18) {
        int t = threadIdx.x;
        sS1[t] = 0; sQ1[t] = 0; sS2[t] = 0; sQ2[t] = 0;
        return;
    }
    int tid = blockIdx.x * 256 + threadIdx.x;       // 0..4607
    if (tid >= 4608) return;
    int set = tid / 2304;
    int r = tid - set * 2304;
    int pat = r >> 8, co = r & 255;
    int pv = pat / 3, pq = pat - pv * 3;
    const int* pc = set ? pc2 : pc1;
    int k = 0, corr = 0;
#pragma unroll
    for (int t = 0; t < 9; ++t) {
        int ty = t / 3, tx = t - ty * 3;
        bool inv = (pv == 0 && ty == 0) || (pv == 2 && ty == 2) ||
                   (pq == 0 && tx == 0) || (pq == 2 && tx == 2);
        if (inv) {
            ++k;
            const int* p = pc + (co * 9 + t) * 4;
            corr += p[0] + p[1] + p[2] + p[3];
        }
    }
    unsigned short* K = set ? K2 : K1;
    K[pat * 256 + co] = (unsigned short)(256 * (9 - k) + 2 * corr);
}

// ==== pack activations into [n][ph][pw][wd] u64 (wd innermost, 32B/pixel) ====
// Main: wave = 64-pixel group, 256 channel ballots + 4 transposes.
// Tail blocks: zero halo cells of BOTH px buffers.
__global__ __launch_bounds__(256) void pack_act(const float* __restrict__ x,
                                                uint64_t* __restrict__ px1,
                                                uint64_t* __restrict__ px2) {
    if (blockIdx.x >= 392) {                        // halo zeroing mode
        int u = (blockIdx.x - 392) * 256 + threadIdx.x;   // 0..29183
        if (u >= 29184) return;
        int wd = u & 3, v = u >> 2;                 // cell 0..7295
        int n = v / 228, cell = v - n * 228;
        int ph, pw_;
        if (cell < 58)       { ph = 0;          pw_ = cell; }
        else if (cell < 116) { ph = 57;         pw_ = cell - 58; }
        else if (cell < 172) { ph = cell - 115; pw_ = 0; }
        else                 { ph = cell - 171; pw_ = 57; }
        size_t idx = ((size_t)n * PHW + (size_t)ph * PW + pw_) * 4 + wd;
        px1[idx] = 0ull;
        px2[idx] = 0ull;
        return;
    }
    int g = blockIdx.x * 4 + (threadIdx.x >> 6);    // pixel group 0..1567
    int lane = threadIdx.x & 63;
    int n = g / 49, gi = g - n * 49;
    const float* xp = x + (size_t)n * C * HW + gi * 64 + lane;
    uint64_t M[4];
#pragma unroll
    for (int wd = 0; wd < 4; ++wd) {
        uint64_t Mq = 0;
#pragma unroll
        for (int c = 0; c < 64; ++c) {
            float v = xp[(size_t)(wd * 64 + c) * HW];
            unsigned long long m = __ballot(v >= 0.0f);
            if (lane == c) Mq = m;
        }
        M[wd] = bt64(Mq, lane);                     // lane p: bit c
    }
    int p = gi * 64 + lane;
    int h = p / WW, w = p - h * WW;
    uint64_t* dst = px1 + ((size_t)n * PHW + (size_t)(h + 1) * PW + (w + 1)) * 4;
    ((ulonglong2*)dst)[0] = make_ulonglong2(M[0], M[1]);
    ((ulonglong2*)dst)[1] = make_ulonglong2(M[2], M[3]);
}

// ========== binary conv: thread = co, block = row, sliding tap window ========
// Taps wave-uniform -> SGPR sliding window (3 cols x 3 rows x 4 wd u64).
// Weights: 36 u64 per-lane VGPRs, volatile-loaded exactly once.
// Output channel-last s16[p][co] (coalesced); BN stats fused via atomics.
__global__ __launch_bounds__(256, 2) void bconv(const uint64_t* __restrict__ px,
                                                const uint64_t* __restrict__ pwt,
                                                const unsigned short* __restrict__ Kt,
                                                short* __restrict__ sout,
                                                int* __restrict__ sS,
                                                unsigned long long* __restrict__ sQ) {
    int co = threadIdx.x;
    uint64_t wv[36];
    const volatile uint64_t* wq = (const volatile uint64_t*)(pwt + (size_t)co * 40);
#pragma unroll
    for (int i = 0; i < 36; ++i) wv[i] = wq[i];

    int row = blockIdx.x;                           // 0..1791
    int n = row / HH, h = row - n * HH;
    int pv = (h == 0) ? 0 : ((h == HH - 1) ? 2 : 1);
    int K0 = Kt[(pv * 3 + 0) * 256 + co];
    int K1 = Kt[(pv * 3 + 1) * 256 + co];
    int K2 = Kt[(pv * 3 + 2) * 256 + co];

    // padded row h is the top tap row for output row h
    const uint64_t* base = px + (size_t)(n * PHW + h * PW) * 4;
    short* orow = sout + (size_t)(n * HW + h * WW) * C + co;

    uint64_t cA[12], cB[12], cC[12];                // [row k][wd]
#pragma unroll
    for (int k = 0; k < 3; ++k)
#pragma unroll
        for (int wd = 0; wd < 4; ++wd) {
            cA[k * 4 + wd] = base[(size_t)(k * PW + 0) * 4 + wd];
            cB[k * 4 + wd] = base[(size_t)(k * PW + 1) * 4 + wd];
        }

    int ssum = 0, ssq = 0;
#pragma unroll 4
    for (int w = 0; w < WW; ++w) {
#pragma unroll
        for (int k = 0; k < 3; ++k)
#pragma unroll
            for (int wd = 0; wd < 4; ++wd)
                cC[k * 4 + wd] = base[(size_t)(k * PW + w + 2) * 4 + wd];
        int acc = 0;
#pragma unroll
        for (int k = 0; k < 3; ++k)
#pragma unroll
            for (int wd = 0; wd < 4; ++wd) {
                acc += __popcll(cA[k * 4 + wd] ^ wv[wd * 9 + k * 3 + 0]);
                acc += __popcll(cB[k * 4 + wd] ^ wv[wd * 9 + k * 3 + 1]);
                acc += __popcll(cC[k * 4 + wd] ^ wv[wd * 9 + k * 3 + 2]);
            }
        int Ksel = (w == 0) ? K0 : ((w == WW - 1) ? K2 : K1);
        int dot = Ksel - 2 * acc;
        orow[(size_t)w * C] = (short)dot;
        ssum += dot;
        ssq  += dot * dot;                          // <= 56*2304^2 = 2.97e8, fits
#pragma unroll
        for (int i = 0; i < 12; ++i) { cA[i] = cB[i]; cB[i] = cC[i]; }
    }
    atomicAdd(sS + co, ssum);
    atomicAdd(sQ + co, (unsigned long long)(unsigned int)ssq);
}

// ==== bn1 + sign + repack: lane = channel -> ballot IS the packed word =======
// A/B recomputed per-thread from fused integer sums (no separate bnAB pass).
__global__ __launch_bounds__(256) void bnpack(const short* __restrict__ s,
                                              const int* __restrict__ sS,
                                              const unsigned long long* __restrict__ sQ,
                                              const float* __restrict__ g,
                                              const float* __restrict__ b,
                                              uint64_t* __restrict__ px) {
    int gq = blockIdx.x * 4 + (threadIdx.x >> 6);   // pixel group 0..1567
    int lane = threadIdx.x & 63;
    float Aq[4], Bq[4];
#pragma unroll
    for (int wd = 0; wd < 4; ++wd) {
        int c = wd * 64 + lane;
        float S = (float)sS[c];
        float Q = (float)sQ[c];
        float m  = 0.5f  * S / (float)P_TOT;
        float e2 = 0.25f * Q / (float)P_TOT;
        float a = g[c] * rsqrtf(e2 - m * m + EPSBN);
        Aq[wd] = 0.5f * a;                          // y = dot*Aq + Bq
        Bq[wd] = b[c] - m * a;
    }
    int n = gq / 49, gi = gq - n * 49;
    int P0 = n * HW + gi * 64;
    uint64_t M[4] = {0, 0, 0, 0};
#pragma unroll 2
    for (int pi = 0; pi < 64; ++pi) {
        const short* sp = s + (size_t)(P0 + pi) * C + lane;
#pragma unroll
        for (int wd = 0; wd < 4; ++wd) {
            float y = (float)sp[wd * 64] * Aq[wd] + Bq[wd];
            unsigned long long m = __ballot(y >= 0.0f);
            if (lane == pi) M[wd] = m;              // bit j = channel wd*64+j
        }
    }
    int p = gi * 64 + lane;
    int h = p / WW, w = p - h * WW;
    uint64_t* dst = px + ((size_t)n * PHW + (size_t)(h + 1) * PW + (w + 1)) * 4;
    ((ulonglong2*)dst)[0] = make_ulonglong2(M[0], M[1]);
    ((ulonglong2*)dst)[1] = make_ulonglong2(M[2], M[3]);
}

// ==== bn2 + shortcut + hardtanh: LDS transpose tile; A/B from fused sums =====
__global__ __launch_bounds__(256) void finalize(const short* __restrict__ s,
                                                const float* __restrict__ x,
                                                const int* __restrict__ sS,
                                                const unsigned long long* __restrict__ sQ,
                                                const float* __restrict__ g,
                                                const float* __restrict__ b,
                                                float* __restrict__ out) {
    __shared__ float sA[256], sB[256];
    __shared__ int4 lds4[2048];                     // 64 px x 512B, slot-swizzled
    int tid = threadIdx.x;
    {
        float S = (float)sS[tid];
        float Q = (float)sQ[tid];
        float m  = 0.5f  * S / (float)P_TOT;
        float e2 = 0.25f * Q / (float)P_TOT;
        float a = g[tid] * rsqrtf(e2 - m * m + EPSBN);
        sA[tid] = 0.5f * a;
        sB[tid] = b[tid] - m * a;
    }
    int p0 = blockIdx.x * 64;
    int n = p0 / HW, rem0 = p0 - n * HW;
    const int4* s4 = (const int4*)(s + (size_t)p0 * C);
#pragma unroll
    for (int it = 0; it < 8; ++it) {
        int u = tid + it * 256;
        int r = u >> 5, j = u & 31;
        lds4[r * 32 + ((j + r) & 31)] = s4[r * 32 + j];
    }
    __syncthreads();
    int lane = tid & 63, wvn = tid >> 6;
#pragma unroll 4
    for (int it = 0; it < 64; ++it) {
        int c = it * 4 + wvn;
        int slot = ((c >> 3) + lane) & 31;
        short sv = ((const short*)lds4)[lane * 256 + slot * 8 + (c & 7)];
        size_t gi = ((size_t)n * C + c) * HW + rem0 + lane;
        float yv = (float)sv * sA[c] + sB[c] + x[gi];
        out[gi] = fminf(1.0f, fmaxf(-1.0f, yv));
    }
}

extern "C" void kernel_launch(void* const* d_in, const int* in_sizes, int n_in,
                              void* d_out, int out_size, void* d_ws, size_t ws_size,
                              hipStream_t stream) {
    const float* x  = (const float*)d_in[0];
    const float* w1 = (const float*)d_in[1];
    const float* g1 = (const float*)d_in[2];
    const float* b1 = (const float*)d_in[3];
    const float* w2 = (const float*)d_in[4];
    const float* g2 = (const float*)d_in[5];
    const float* b2 = (const float*)d_in[6];
    float* out = (float*)d_out;

    // workspace layout (~58.5 MB)
    char* ws = (char*)d_ws;
    uint64_t* pwt1 = (uint64_t*)ws;           ws += 256 * 40 * 8;          // 81,920
    uint64_t* pwt2 = (uint64_t*)ws;           ws += 256 * 40 * 8;
    int* pc1 = (int*)ws;                      ws += 9216 * 4;              // 36,864
    int* pc2 = (int*)ws;                      ws += 9216 * 4;
    unsigned short* K1 = (unsigned short*)ws; ws += 8192;
    unsigned short* K2 = (unsigned short*)ws; ws += 8192;
    int* sS1 = (int*)ws;                      ws += 1024;
    int* sS2 = (int*)ws;                      ws += 1024;
    unsigned long long* sQ1 = (unsigned long long*)ws; ws += 2048;
    unsigned long long* sQ2 = (unsigned long long*)ws; ws += 2048;
    uint64_t* px1 = (uint64_t*)ws;            ws += (size_t)4 * NPAD * 8;  // 3,444,736
    uint64_t* px2 = (uint64_t*)ws;            ws += (size_t)4 * NPAD * 8;
    short* s16 = (short*)ws;                  // 51,380,224, channel-last [p][c]

    pack_wgt<<<4608, 256, 0, stream>>>(w1, w2, pwt1, pwt2, pc1, pc2);
    build_K<<<19, 256, 0, stream>>>(pc1, pc2, K1, K2, sS1, sQ1, sS2, sQ2);
    pack_act<<<392 + 114, 256, 0, stream>>>(x, px1, px2);

    bconv<<<NB * HH, 256, 0, stream>>>(px1, pwt1, K1, s16, sS1, sQ1);
    bnpack<<<392, 256, 0, stream>>>(s16, sS1, sQ1, g1, b1, px2);

    bconv<<<NB * HH, 256, 0, stream>>>(px2, pwt2, K2, s16, sS2, sQ2);

    finalize<<<1568, 256, 0, stream>>>(s16, x, sS2, sQ2, g2, b2, out);
}